// Round 2
// baseline (1183.889 us; speedup 1.0000x reference)
//
#include <hip/hip_runtime.h>

#define Bn 32
#define Kn 512
#define Cn 32

typedef float vf4 __attribute__((ext_vector_type(4)));

// ws layout (float offsets)
#define WTC_OFF   0          // 16384: w_col transposed  wTc[k*32+o]
#define WTR_OFF   16384      // 16384: w_row transposed
#define COL_OFF   32768      // 524288: colPlus[b][t][o] (bias included)
#define ROW_OFF   557056     // 524288: rowPlus[b][t][o]
#define S_OFF     1081344    // 1024: s[b*32+o]

// ---------------- k0: transpose weights to k-major ----------------
__global__ void k_transpose_w(const float* __restrict__ w_col,
                              const float* __restrict__ w_row,
                              float* __restrict__ ws) {
    int idx = blockIdx.x * blockDim.x + threadIdx.x;   // 0..32767
    int which = idx >> 14;                             // 0: col, 1: row
    int e = idx & 16383;
    int o = e & 31, k = e >> 5;
    const float* src = which ? w_row : w_col;
    float* dst = ws + (which ? WTR_OFF : WTC_OFF);
    dst[e] = src[o * Kn + k];
}

// ---------------- k1: col/row skinny GEMMs ----------------
// grid (4 t-chunks, 32 b, 2 phases), 256 threads.
// thread = (t = tid&127, kh = tid>>7); acc[32] over o; k-half split, LDS pair-reduce.
__global__ __launch_bounds__(256) void k_colrow(
    const float* __restrict__ x,      // [B][K][K]
    const float* __restrict__ bcol,
    const float* __restrict__ brow,
    float* __restrict__ ws) {
    const int chunk = blockIdx.x;     // 0..3
    const int b     = blockIdx.y;     // 0..31
    const int phase = blockIdx.z;     // 0 = col, 1 = row
    const int t0  = chunk * 128;
    const int tid = threadIdx.x;
    const int t   = tid & 127;
    const int kh  = tid >> 7;

    __shared__ float s_x[64 * 129];   // staging tile; reused as red[128][33]

    const float* __restrict__ wT = ws + (phase ? WTR_OFF : WTC_OFF);
    const float* __restrict__ xb = x + b * (Kn * Kn);

    float acc[32];
#pragma unroll
    for (int o = 0; o < 32; ++o) acc[o] = 0.f;

    if (phase == 0) {
        // col[t,o] = sum_k x[t0+t][k] * wT[k][o] — rows of X, staged transposed in LDS
        const float4* x4 = (const float4*)xb;
        for (int tile = 0; tile < 8; ++tile) {
            __syncthreads();
#pragma unroll
            for (int i = 0; i < 8; ++i) {
                int idx4 = tid + i * 256;          // 0..2047
                int tl = idx4 >> 4;                // 0..127
                int k4 = idx4 & 15;                // 0..15 (float4 within 64-k tile)
                float4 v = x4[(t0 + tl) * 128 + tile * 16 + k4];
                s_x[(k4 * 4 + 0) * 129 + tl] = v.x;
                s_x[(k4 * 4 + 1) * 129 + tl] = v.y;
                s_x[(k4 * 4 + 2) * 129 + tl] = v.z;
                s_x[(k4 * 4 + 3) * 129 + tl] = v.w;
            }
            __syncthreads();
            const int kkb = kh * 32;
            const float* __restrict__ wTt = wT + (tile * 64 + kkb) * 32;
#pragma unroll 4
            for (int kk = 0; kk < 32; ++kk) {
                float xv = s_x[(kkb + kk) * 129 + t];   // lanes: consecutive t → conflict-free
                const float* __restrict__ w = wTt + kk * 32;  // wave-uniform → s_load
#pragma unroll
                for (int o = 0; o < 32; ++o) acc[o] = fmaf(xv, w[o], acc[o]);
            }
        }
    } else {
        // row[t,o] = sum_k x[k][t0+t] * wT[k][o] — lanes on consecutive t: coalesced, no LDS
        const int kb = kh * 256;
#pragma unroll 4
        for (int k = 0; k < 256; ++k) {
            float xv = xb[(kb + k) * Kn + t0 + t];
            const float* __restrict__ w = wT + (kb + k) * 32;
#pragma unroll
            for (int o = 0; o < 32; ++o) acc[o] = fmaf(xv, w[o], acc[o]);
        }
    }

    // reduce the two k-halves via LDS, add bias, store
    float* red = s_x;                 // [128][33] padded
    __syncthreads();
    if (kh == 1) {
#pragma unroll
        for (int o = 0; o < 32; ++o) red[t * 33 + o] = acc[o];
    }
    __syncthreads();
    if (kh == 0) {
        const float* __restrict__ bias = phase ? brow : bcol;
        float* __restrict__ dst = ws + (phase ? ROW_OFF : COL_OFF) + (b * Kn + t0 + t) * 32;
#pragma unroll
        for (int o = 0; o < 32; ++o)
            dst[o] = acc[o] + red[t * 33 + o] + bias[o];
    }
}

// ---------------- k1b: s[b,o] = sum_t rowPlus*colPlus ----------------
__global__ void k_reduce(float* __restrict__ ws) {
    const int b = blockIdx.x;
    const int tid = threadIdx.x;
    const int o = tid & 31, tp = tid >> 5;       // 8 t-groups
    const float* __restrict__ cp = ws + COL_OFF + b * (Kn * 32);
    const float* __restrict__ rp = ws + ROW_OFF + b * (Kn * 32);
    float sum = 0.f;
    for (int j = 0; j < 64; ++j) {
        int tt = tp * 64 + j;
        sum += cp[tt * 32 + o] * rp[tt * 32 + o];
    }
    __shared__ float red[8 * 33];
    red[tp * 33 + o] = sum;
    __syncthreads();
    if (tid < 32) {
        float s = 0.f;
#pragma unroll
        for (int j = 0; j < 8; ++j) s += red[j * 33 + tid];
        ws[S_OFF + b * 32 + tid] = s;
    }
}

// ---------------- k2: broadcast s to (B,C,512,512) ----------------
// 16384 blocks × 256 threads × 16 float4 = 1 GiB, fully coalesced nt stores.
__global__ __launch_bounds__(256) void k_broadcast(const float* __restrict__ ws,
                                                   float* __restrict__ out) {
    const int bo   = blockIdx.x >> 4;            // 0..1023
    const int part = blockIdx.x & 15;
    const float sval = ws[S_OFF + bo];           // uniform → s_load
    vf4 v = (vf4){sval, sval, sval, sval};
    vf4* __restrict__ out4 =
        (vf4*)out + (size_t)bo * 65536 + (size_t)part * 4096 + threadIdx.x;
#pragma unroll
    for (int j = 0; j < 16; ++j)
        __builtin_nontemporal_store(v, out4 + j * 256);
}

extern "C" void kernel_launch(void* const* d_in, const int* in_sizes, int n_in,
                              void* d_out, int out_size, void* d_ws, size_t ws_size,
                              hipStream_t stream) {
    const float* x     = (const float*)d_in[0];
    const float* w_col = (const float*)d_in[1];
    const float* b_col = (const float*)d_in[2];
    const float* w_row = (const float*)d_in[3];
    const float* b_row = (const float*)d_in[4];
    float* out = (float*)d_out;
    float* ws  = (float*)d_ws;

    hipLaunchKernelGGL(k_transpose_w, dim3(128), dim3(256), 0, stream, w_col, w_row, ws);
    hipLaunchKernelGGL(k_colrow, dim3(4, 32, 2), dim3(256), 0, stream, x, b_col, b_row, ws);
    hipLaunchKernelGGL(k_reduce, dim3(32), dim3(256), 0, stream, ws);
    hipLaunchKernelGGL(k_broadcast, dim3(16384), dim3(256), 0, stream, ws, out);
}

// Round 3
// 1146.377 us; speedup vs baseline: 1.0327x; 1.0327x over previous
//
#include <hip/hip_runtime.h>

#define Bn 32
#define Kn 512
#define Cn 32

typedef float vf4 __attribute__((ext_vector_type(4)));

// ws layout (float offsets)
#define WTC_OFF   0          // 16384: w_col transposed  wTc[k*32+o]
#define WTR_OFF   16384      // 16384: w_row transposed
#define COL_OFF   32768      // 524288: colPlus[b][t][o] (bias included)
#define ROW_OFF   557056     // 524288: rowPlus[b][t][o]
#define S_OFF     1081344    // 1024: s[b*32+o]

// ---------------- k0: transpose weights to k-major + zero s ----------------
__global__ void k_prep(const float* __restrict__ w_col,
                       const float* __restrict__ w_row,
                       float* __restrict__ ws) {
    if (blockIdx.x == 128) {             // zero s[1024]
        ((vf4*)(ws + S_OFF))[threadIdx.x] = (vf4){0.f, 0.f, 0.f, 0.f};
        return;
    }
    int idx = blockIdx.x * 256 + threadIdx.x;          // 0..32767
    int which = idx >> 14;                             // 0: col, 1: row
    int e = idx & 16383;
    int o = e & 31, k = e >> 5;
    const float* src = which ? w_row : w_col;
    float* dst = ws + (which ? WTR_OFF : WTC_OFF);
    dst[e] = src[o * Kn + k];
}

// ---------------- k1: col/row skinny GEMMs ----------------
// grid (8 t-chunks, 32 b, 2 phases) = 512 blocks → 2 blocks/CU, 8 waves/CU.
// thread = (t = tid&63, kh = tid>>6 ∈ 0..3); acc[32] over o; 4-way k-split.
__global__ __launch_bounds__(256) void k_colrow(
    const float* __restrict__ x,      // [B][K][K]
    const float* __restrict__ bcol,
    const float* __restrict__ brow,
    float* __restrict__ ws) {
    const int chunk = blockIdx.x;     // 0..7
    const int b     = blockIdx.y;     // 0..31
    const int phase = blockIdx.z;     // 0 = col, 1 = row
    const int t0  = chunk * 64;
    const int tid = threadIdx.x;
    const int t   = tid & 63;
    const int kh  = tid >> 6;         // 0..3

    __shared__ float s_x[64 * 65];    // 16.6 KB staging tile (k × t, pad 65)
    __shared__ float red[2][64 * 33]; // 16.9 KB reduction buffers

    const float* __restrict__ wT = ws + (phase ? WTR_OFF : WTC_OFF);
    const float* __restrict__ xb = x + b * (Kn * Kn);

    float acc[32];
#pragma unroll
    for (int o = 0; o < 32; ++o) acc[o] = 0.f;

    if (phase == 0) {
        // col[t,o] = sum_k x[t0+t][k] * wT[k][o] — rows of X staged transposed
        const float4* x4 = (const float4*)xb;
        for (int tile = 0; tile < 8; ++tile) {
            __syncthreads();
#pragma unroll
            for (int i = 0; i < 4; ++i) {
                int idx4 = tid + i * 256;          // 0..1023
                int tl = idx4 >> 4;                // 0..63
                int k4 = idx4 & 15;                // float4 within 64-k tile
                float4 v = x4[(t0 + tl) * 128 + tile * 16 + k4];
                s_x[(k4 * 4 + 0) * 65 + tl] = v.x;
                s_x[(k4 * 4 + 1) * 65 + tl] = v.y;
                s_x[(k4 * 4 + 2) * 65 + tl] = v.z;
                s_x[(k4 * 4 + 3) * 65 + tl] = v.w;
            }
            __syncthreads();
            const float* __restrict__ wTt = wT + (tile * 64 + kh * 16) * 32;
#pragma unroll
            for (int kk = 0; kk < 16; ++kk) {
                float xv = s_x[(kh * 16 + kk) * 65 + t];  // consecutive t → ≤2-way
                const float* __restrict__ w = wTt + kk * 32;  // uniform → s_load
#pragma unroll
                for (int o = 0; o < 32; ++o) acc[o] = fmaf(xv, w[o], acc[o]);
            }
        }
    } else {
        // row[t,o] = sum_k x[k][t0+t] * wT[k][o] — coalesced column reads, no LDS
        const int kb = kh * 128;
#pragma unroll 8
        for (int k = 0; k < 128; ++k) {
            float xv = xb[(kb + k) * Kn + t0 + t];
            const float* __restrict__ w = wT + (kb + k) * 32;
#pragma unroll
            for (int o = 0; o < 32; ++o) acc[o] = fmaf(xv, w[o], acc[o]);
        }
    }

    // reduce 4 k-groups: kh∈{2,3} → LDS, add into kh∈{0,1}, then pair-reduce
    __syncthreads();
    if (kh >= 2) {
        float* r = red[kh - 2];
#pragma unroll
        for (int o = 0; o < 32; ++o) r[t * 33 + o] = acc[o];
    }
    __syncthreads();
    if (kh < 2) {
        const float* r = red[kh];
#pragma unroll
        for (int o = 0; o < 32; ++o) acc[o] += r[t * 33 + o];
    }
    __syncthreads();
    if (kh == 1) {
#pragma unroll
        for (int o = 0; o < 32; ++o) red[1][t * 33 + o] = acc[o];
    }
    __syncthreads();
    if (kh == 0) {
        const float* __restrict__ bias = phase ? brow : bcol;
        float* __restrict__ dst = ws + (phase ? ROW_OFF : COL_OFF) + (b * Kn + t0 + t) * 32;
#pragma unroll
        for (int o = 0; o < 32; ++o)
            dst[o] = acc[o] + red[1][t * 33 + o] + bias[o];
    }
}

// ---------------- k2: s[b,o] += sum_t rowPlus*colPlus (partial per block) ----------------
// grid 128 = (4 t-groups × 32 b); fp32 atomicAdd into pre-zeroed s.
__global__ void k_reduce(float* __restrict__ ws) {
    const int tg = blockIdx.x & 3, b = blockIdx.x >> 2;
    const int tid = threadIdx.x;
    const int o = tid & 31, tp = tid >> 5;       // 8 sub-groups
    const float* __restrict__ cp = ws + COL_OFF + b * (Kn * 32);
    const float* __restrict__ rp = ws + ROW_OFF + b * (Kn * 32);
    const int tbase = tg * 128 + tp * 16;
    float sum = 0.f;
#pragma unroll
    for (int j = 0; j < 16; ++j) {
        int tt = tbase + j;
        sum += cp[tt * 32 + o] * rp[tt * 32 + o];
    }
    __shared__ float red[8 * 33];
    red[tp * 33 + o] = sum;
    __syncthreads();
    if (tid < 32) {
        float s = 0.f;
#pragma unroll
        for (int j = 0; j < 8; ++j) s += red[j * 33 + tid];
        atomicAdd(ws + S_OFF + b * 32 + tid, s);
    }
}

// ---------------- k3: broadcast s to (B,C,512,512) ----------------
// 16384 blocks × 256 threads × 16 float4 = 1 GiB, fully coalesced nt stores.
__global__ __launch_bounds__(256) void k_broadcast(const float* __restrict__ ws,
                                                   float* __restrict__ out) {
    const int bo   = blockIdx.x >> 4;            // 0..1023
    const int part = blockIdx.x & 15;
    const float sval = ws[S_OFF + bo];           // uniform → s_load
    vf4 v = (vf4){sval, sval, sval, sval};
    vf4* __restrict__ out4 =
        (vf4*)out + (size_t)bo * 65536 + (size_t)part * 4096 + threadIdx.x;
#pragma unroll
    for (int j = 0; j < 16; ++j)
        __builtin_nontemporal_store(v, out4 + j * 256);
}

extern "C" void kernel_launch(void* const* d_in, const int* in_sizes, int n_in,
                              void* d_out, int out_size, void* d_ws, size_t ws_size,
                              hipStream_t stream) {
    const float* x     = (const float*)d_in[0];
    const float* w_col = (const float*)d_in[1];
    const float* b_col = (const float*)d_in[2];
    const float* w_row = (const float*)d_in[3];
    const float* b_row = (const float*)d_in[4];
    float* out = (float*)d_out;
    float* ws  = (float*)d_ws;

    hipLaunchKernelGGL(k_prep, dim3(129), dim3(256), 0, stream, w_col, w_row, ws);
    hipLaunchKernelGGL(k_colrow, dim3(8, 32, 2), dim3(256), 0, stream, x, b_col, b_row, ws);
    hipLaunchKernelGGL(k_reduce, dim3(128), dim3(256), 0, stream, ws);
    hipLaunchKernelGGL(k_broadcast, dim3(16384), dim3(256), 0, stream, ws, out);
}

// Round 4
// 1119.043 us; speedup vs baseline: 1.0579x; 1.0244x over previous
//
#include <hip/hip_runtime.h>

#define Bn 32
#define Kn 512
#define Cn 32

typedef float vf4 __attribute__((ext_vector_type(4)));

// ws layout (float offsets)
#define WTC_OFF   0          // 16384: w_col transposed  wTc[k*32+o]
#define WTR_OFF   16384      // 16384: w_row transposed
#define COL_OFF   32768      // 524288: colPlus[b][t][o] (bias included)
#define ROW_OFF   557056     // 524288: rowPlus[b][t][o]
#define S_OFF     1081344    // 1024: s[b*32+o]

// ---------------- k0: transpose weights to k-major + zero s ----------------
__global__ void k_prep(const float* __restrict__ w_col,
                       const float* __restrict__ w_row,
                       float* __restrict__ ws) {
    if (blockIdx.x == 128) {             // zero s[1024]
        ((vf4*)(ws + S_OFF))[threadIdx.x] = (vf4){0.f, 0.f, 0.f, 0.f};
        return;
    }
    int idx = blockIdx.x * 256 + threadIdx.x;          // 0..32767
    int which = idx >> 14;                             // 0: col, 1: row
    int e = idx & 16383;
    int o = e & 31, k = e >> 5;
    const float* src = which ? w_row : w_col;
    float* dst = ws + (which ? WTR_OFF : WTC_OFF);
    dst[e] = src[o * Kn + k];
}

// ---------------- k1: col/row skinny GEMMs ----------------
// grid (8 t-chunks, 32 b, 2 phases) = 512 blocks → 2 blocks/CU.
// thread = (t = tid&63 = lane, kh = wave id 0..3); acc[32] over o; 4-way k-split.
// kh is readfirstlane'd so ALL weight reads are wave-uniform → s_load (SGPR
// broadcast), leaving exactly one per-lane VMEM op per 4 k (phase0) / per k
// (phase1). No LDS staging, no barriers in the main loop.
__global__ __launch_bounds__(256) void k_colrow(
    const float* __restrict__ x,      // [B][K][K]
    const float* __restrict__ bcol,
    const float* __restrict__ brow,
    float* __restrict__ ws) {
    const int chunk = blockIdx.x;     // 0..7
    const int b     = blockIdx.y;     // 0..31
    const int phase = blockIdx.z;     // 0 = col, 1 = row
    const int t0  = chunk * 64;
    const int tid = threadIdx.x;
    const int t   = tid & 63;                                   // lane
    const int kh  = __builtin_amdgcn_readfirstlane(tid >> 6);   // wave-uniform 0..3

    __shared__ float red[2][64 * 33]; // 16.9 KB reduction buffers

    const float* __restrict__ wT = ws + (phase ? WTR_OFF : WTC_OFF);
    const float* __restrict__ xb = x + b * (Kn * Kn);

    float acc[32];
#pragma unroll
    for (int o = 0; o < 32; ++o) acc[o] = 0.f;

    if (phase == 0) {
        // col[t,o] = sum_k x[t0+t][k] * wT[k][o] — per-thread contiguous row reads
        const float4* __restrict__ xr = (const float4*)(xb + (t0 + t) * Kn) + kh * 32;
        const float* __restrict__ wk = wT + kh * 128 * 32;
#pragma unroll 2
        for (int j = 0; j < 32; ++j) {                 // 32 float4 = 128 k
            float4 v = xr[j];
            const float* __restrict__ w0 = wk + j * 128;   // uniform → s_load
#pragma unroll
            for (int o = 0; o < 32; ++o) acc[o] = fmaf(v.x, w0[o],      acc[o]);
#pragma unroll
            for (int o = 0; o < 32; ++o) acc[o] = fmaf(v.y, w0[32 + o], acc[o]);
#pragma unroll
            for (int o = 0; o < 32; ++o) acc[o] = fmaf(v.z, w0[64 + o], acc[o]);
#pragma unroll
            for (int o = 0; o < 32; ++o) acc[o] = fmaf(v.w, w0[96 + o], acc[o]);
        }
    } else {
        // row[t,o] = sum_k x[k][t0+t] * wT[k][o] — lane-contiguous column reads
        const int kb = kh * 128;
#pragma unroll 4
        for (int k = 0; k < 128; ++k) {
            float xv = xb[(kb + k) * Kn + t0 + t];
            const float* __restrict__ w = wT + (kb + k) * 32;  // uniform → s_load
#pragma unroll
            for (int o = 0; o < 32; ++o) acc[o] = fmaf(xv, w[o], acc[o]);
        }
    }

    // reduce 4 k-groups: kh∈{2,3} → LDS, add into kh∈{0,1}, then pair-reduce
    __syncthreads();
    if (kh >= 2) {
        float* r = red[kh - 2];
#pragma unroll
        for (int o = 0; o < 32; ++o) r[t * 33 + o] = acc[o];
    }
    __syncthreads();
    if (kh < 2) {
        const float* r = red[kh];
#pragma unroll
        for (int o = 0; o < 32; ++o) acc[o] += r[t * 33 + o];
    }
    __syncthreads();
    if (kh == 1) {
#pragma unroll
        for (int o = 0; o < 32; ++o) red[1][t * 33 + o] = acc[o];
    }
    __syncthreads();
    if (kh == 0) {
        const float* __restrict__ bias = phase ? brow : bcol;
        float* __restrict__ dst = ws + (phase ? ROW_OFF : COL_OFF) + (b * Kn + t0 + t) * 32;
#pragma unroll
        for (int o = 0; o < 32; ++o)
            dst[o] = acc[o] + red[1][t * 33 + o] + bias[o];
    }
}

// ---------------- k2: s[b,o] += sum_t rowPlus*colPlus (partial per block) ----------------
// grid 128 = (4 t-groups × 32 b); fp32 atomicAdd into pre-zeroed s.
__global__ void k_reduce(float* __restrict__ ws) {
    const int tg = blockIdx.x & 3, b = blockIdx.x >> 2;
    const int tid = threadIdx.x;
    const int o = tid & 31, tp = tid >> 5;       // 8 sub-groups
    const float* __restrict__ cp = ws + COL_OFF + b * (Kn * 32);
    const float* __restrict__ rp = ws + ROW_OFF + b * (Kn * 32);
    const int tbase = tg * 128 + tp * 16;
    float sum = 0.f;
#pragma unroll
    for (int j = 0; j < 16; ++j) {
        int tt = tbase + j;
        sum += cp[tt * 32 + o] * rp[tt * 32 + o];
    }
    __shared__ float red[8 * 33];
    red[tp * 33 + o] = sum;
    __syncthreads();
    if (tid < 32) {
        float s = 0.f;
#pragma unroll
        for (int j = 0; j < 8; ++j) s += red[j * 33 + tid];
        atomicAdd(ws + S_OFF + b * 32 + tid, s);
    }
}

// ---------------- k3: broadcast s to (B,C,512,512) ----------------
// 16384 blocks × 256 threads × 16 float4 = 1 GiB, fully coalesced nt stores.
__global__ __launch_bounds__(256) void k_broadcast(const float* __restrict__ ws,
                                                   float* __restrict__ out) {
    const int bo   = blockIdx.x >> 4;            // 0..1023
    const int part = blockIdx.x & 15;
    const float sval = ws[S_OFF + bo];           // uniform → s_load
    vf4 v = (vf4){sval, sval, sval, sval};
    vf4* __restrict__ out4 =
        (vf4*)out + (size_t)bo * 65536 + (size_t)part * 4096 + threadIdx.x;
#pragma unroll
    for (int j = 0; j < 16; ++j)
        __builtin_nontemporal_store(v, out4 + j * 256);
}

extern "C" void kernel_launch(void* const* d_in, const int* in_sizes, int n_in,
                              void* d_out, int out_size, void* d_ws, size_t ws_size,
                              hipStream_t stream) {
    const float* x     = (const float*)d_in[0];
    const float* w_col = (const float*)d_in[1];
    const float* b_col = (const float*)d_in[2];
    const float* w_row = (const float*)d_in[3];
    const float* b_row = (const float*)d_in[4];
    float* out = (float*)d_out;
    float* ws  = (float*)d_ws;

    hipLaunchKernelGGL(k_prep, dim3(129), dim3(256), 0, stream, w_col, w_row, ws);
    hipLaunchKernelGGL(k_colrow, dim3(8, 32, 2), dim3(256), 0, stream, x, b_col, b_row, ws);
    hipLaunchKernelGGL(k_reduce, dim3(128), dim3(256), 0, stream, ws);
    hipLaunchKernelGGL(k_broadcast, dim3(16384), dim3(256), 0, stream, ws, out);
}

// Round 5
// 1101.632 us; speedup vs baseline: 1.0747x; 1.0158x over previous
//
#include <hip/hip_runtime.h>

#define Bn 32
#define Kn 512
#define Cn 32

typedef float vf4 __attribute__((ext_vector_type(4)));

// ws layout (float offsets)
#define WTC_OFF   0          // 16384: w_col transposed  wTc[k*32+o]
#define WTR_OFF   16384      // 16384: w_row transposed
#define S_OFF     32768      // 1024: s[b*32+o]

// ---------------- k0: transpose weights to k-major + zero s ----------------
__global__ void k_prep(const float* __restrict__ w_col,
                       const float* __restrict__ w_row,
                       float* __restrict__ ws) {
    if (blockIdx.x == 128) {             // zero s[1024]
        ((vf4*)(ws + S_OFF))[threadIdx.x] = (vf4){0.f, 0.f, 0.f, 0.f};
        return;
    }
    int idx = blockIdx.x * 256 + threadIdx.x;          // 0..32767
    int which = idx >> 14;                             // 0: col, 1: row
    int e = idx & 16383;
    int o = e & 31, k = e >> 5;
    const float* src = which ? w_row : w_col;
    float* dst = ws + (which ? WTR_OFF : WTC_OFF);
    dst[e] = src[o * Kn + k];
}

// ---------------- k1: fused col/row GEMMs + dot-reduce → s ----------------
// grid (8 t-chunks, 32 b) = 256 blocks × 512 threads (8 waves) → 8 waves/CU.
// wave w: phase = w>>2 (0=col, 1=row), kh = w&3 (k-quarter); lane = t (0..63).
// k is wave-uniform ⇒ all weight reads are SGPR s_loads (per round-4 win).
// Per-wave accs → LDS, block forms colPlus·rowPlus, atomicAdd 32 partials.
__global__ __launch_bounds__(512) void k_fused(
    const float* __restrict__ x,      // [B][K][K]
    const float* __restrict__ bcol,
    const float* __restrict__ brow,
    float* __restrict__ ws) {
    const int chunk = blockIdx.x;     // 0..7
    const int b     = blockIdx.y;     // 0..31
    const int t0  = chunk * 64;
    const int tid = threadIdx.x;
    const int t   = tid & 63;                                   // lane
    const int wv  = __builtin_amdgcn_readfirstlane(tid >> 6);   // 0..7
    const int phase = wv >> 2;
    const int kh    = wv & 3;

    __shared__ float buf[8][64 * 33]; // 67.6 KB

    const float* __restrict__ xb = x + b * (Kn * Kn);

    float acc[32];
#pragma unroll
    for (int o = 0; o < 32; ++o) acc[o] = 0.f;

    if (phase == 0) {
        // col[t,o] = sum_k x[t0+t][k] * wTc[k][o] — per-thread contiguous rows
        const float4* __restrict__ xr = (const float4*)(xb + (t0 + t) * Kn) + kh * 32;
        const float* __restrict__ wk = ws + WTC_OFF + kh * 128 * 32;
#pragma unroll 2
        for (int j = 0; j < 32; ++j) {                 // 32 float4 = 128 k
            float4 v = xr[j];
            const float* __restrict__ w0 = wk + j * 128;   // uniform → s_load
#pragma unroll
            for (int o = 0; o < 32; ++o) acc[o] = fmaf(v.x, w0[o],      acc[o]);
#pragma unroll
            for (int o = 0; o < 32; ++o) acc[o] = fmaf(v.y, w0[32 + o], acc[o]);
#pragma unroll
            for (int o = 0; o < 32; ++o) acc[o] = fmaf(v.z, w0[64 + o], acc[o]);
#pragma unroll
            for (int o = 0; o < 32; ++o) acc[o] = fmaf(v.w, w0[96 + o], acc[o]);
        }
    } else {
        // row[t,o] = sum_k x[k][t0+t] * wTr[k][o] — lane-contiguous column reads
        const float* __restrict__ wr = ws + WTR_OFF;
        const int kb = kh * 128;
#pragma unroll 4
        for (int k = 0; k < 128; ++k) {
            float xv = xb[(kb + k) * Kn + t0 + t];
            const float* __restrict__ w = wr + (kb + k) * 32;  // uniform → s_load
#pragma unroll
            for (int o = 0; o < 32; ++o) acc[o] = fmaf(xv, w[o], acc[o]);
        }
    }

    // park all 8 wave-accumulators in LDS (banks: (33t+o)%32 = (t+o)%32, clean)
    {
        float* __restrict__ my = buf[wv] + t * 33;
#pragma unroll
        for (int o = 0; o < 32; ++o) my[o] = acc[o];
    }
    __syncthreads();

    // product-reduce: 512 threads, o = tid&31, g = tid>>5 covers 4 t each
    const int o = tid & 31, g = tid >> 5;            // g: 0..15
    const float bc = bcol[o], br = brow[o];
    float sum = 0.f;
#pragma unroll
    for (int j = 0; j < 4; ++j) {
        const int tt = g * 4 + j;
        const int a  = tt * 33 + o;
        float c = buf[0][a] + buf[1][a] + buf[2][a] + buf[3][a] + bc;
        float r = buf[4][a] + buf[5][a] + buf[6][a] + buf[7][a] + br;
        sum = fmaf(c, r, sum);
    }
    __shared__ float red2[16 * 33];
    red2[g * 33 + o] = sum;
    __syncthreads();
    if (tid < 32) {
        float s = 0.f;
#pragma unroll
        for (int j = 0; j < 16; ++j) s += red2[j * 33 + tid];
        atomicAdd(ws + S_OFF + b * 32 + tid, s);
    }
}

// ---------------- k2: broadcast s to (B,C,512,512) ----------------
// 16384 blocks × 256 threads × 16 float4 = 1 GiB, fully coalesced nt stores.
__global__ __launch_bounds__(256) void k_broadcast(const float* __restrict__ ws,
                                                   float* __restrict__ out) {
    const int bo   = blockIdx.x >> 4;            // 0..1023
    const int part = blockIdx.x & 15;
    const float sval = ws[S_OFF + bo];           // uniform → s_load
    vf4 v = (vf4){sval, sval, sval, sval};
    vf4* __restrict__ out4 =
        (vf4*)out + (size_t)bo * 65536 + (size_t)part * 4096 + threadIdx.x;
#pragma unroll
    for (int j = 0; j < 16; ++j)
        __builtin_nontemporal_store(v, out4 + j * 256);
}

extern "C" void kernel_launch(void* const* d_in, const int* in_sizes, int n_in,
                              void* d_out, int out_size, void* d_ws, size_t ws_size,
                              hipStream_t stream) {
    const float* x     = (const float*)d_in[0];
    const float* w_col = (const float*)d_in[1];
    const float* b_col = (const float*)d_in[2];
    const float* w_row = (const float*)d_in[3];
    const float* b_row = (const float*)d_in[4];
    float* out = (float*)d_out;
    float* ws  = (float*)d_ws;

    hipLaunchKernelGGL(k_prep, dim3(129), dim3(256), 0, stream, w_col, w_row, ws);
    hipLaunchKernelGGL(k_fused, dim3(8, 32), dim3(512), 0, stream, x, b_col, b_row, ws);
    hipLaunchKernelGGL(k_broadcast, dim3(16384), dim3(256), 0, stream, ws, out);
}